// Round 2
// baseline (172.488 us; speedup 1.0000x reference)
//
#include <hip/hip_runtime.h>
#include <hip/hip_bf16.h>

using u16 = unsigned short;
using u32 = unsigned int;

typedef __attribute__((ext_vector_type(8))) short bf16x8;
typedef __attribute__((ext_vector_type(4))) float f32x4;
typedef __attribute__((ext_vector_type(4))) u32 u32x4;

#define MFMA16(a, b, c) __builtin_amdgcn_mfma_f32_16x16x32_bf16((a), (b), (c), 0, 0, 0)

union FragU { u32 u[4]; bf16x8 v; };

__device__ __forceinline__ bf16x8 mk_frag(u32 a, u32 b, u32 c, u32 d) {
  FragU f; f.u[0] = a; f.u[1] = b; f.u[2] = c; f.u[3] = d; return f.v;
}

__device__ __forceinline__ u16 f2bf(float x) {
  __hip_bfloat16 h = __float2bfloat16(x);
  u16 r; __builtin_memcpy(&r, &h, 2); return r;
}

__device__ __forceinline__ u32 pk_bf16(float a, float b) {
  __hip_bfloat162 h = __float22bfloat162_rn(make_float2(a, b));
  u32 r; __builtin_memcpy(&r, &h, 4); return r;
}

__device__ __forceinline__ float fast_tanh(float x) {
  // tanh(x) = 1 - 2/(1 + exp2(x * 2*log2(e)))
  float t = __builtin_amdgcn_exp2f(x * 2.885390081777927f);
  return __builtin_fmaf(-2.0f, __builtin_amdgcn_rcpf(1.0f + t), 1.0f);
}

__device__ __forceinline__ u32 lo16(u32 x, u32 y) { return (x & 0xffffu) | (y << 16); }
__device__ __forceinline__ u32 hi16(u32 x, u32 y) { return (x >> 16) | (y & 0xffff0000u); }

#define LDS_W2 0
#define LDS_W3 32768
#define LDS_HB 65536          // 8 waves * 8192 B per-wave hbuf
#define LDS_W4 131072         // 512 B
#define LDS_TOTAL 131584

// hbuf layout: dword(row, d) holds (tile0, tile1) bf16 pair for hidden dim n==d,
// swizzled d' = d ^ (row<<2) -> max 2-way bank aliasing on both sides (free, m136).
// W2T/W3T layout: row n (256 B), 16B chunk kc stored at kc ^ (n&15).

__global__ void __launch_bounds__(512) mlp_fused(
    const float* __restrict__ Xg, const float* __restrict__ Yg,
    const float* __restrict__ C1g, const float* __restrict__ C2g,
    const float* __restrict__ W1g, const float* __restrict__ B1g,
    const float* __restrict__ W2g, const float* __restrict__ B2g,
    const float* __restrict__ W3g, const float* __restrict__ B3g,
    const float* __restrict__ W4g, const float* __restrict__ B4g,
    float* __restrict__ Og, int npts, int nwaves_total)
{
  extern __shared__ char lds[];
  const int tid = threadIdx.x;

  // ---- stage W2^T, W3^T (swizzled) and W4^T into LDS, f32 -> bf16 ----
  for (int i = tid; i < 16384; i += 512) {
    int k = i >> 7, n = i & 127;
    int off = n * 256 + ((((k >> 3) ^ (n & 15)) << 4) | ((k & 7) << 1));
    *(u16*)(lds + LDS_W2 + off) = f2bf(W2g[i]);
    *(u16*)(lds + LDS_W3 + off) = f2bf(W3g[i]);
  }
  if (tid < 256) {
    int k = tid >> 1, o = tid & 1;   // W4 is [128][2] row-major
    *(u16*)(lds + LDS_W4 + o * 256 + k * 2) = f2bf(W4g[tid]);
  }
  __syncthreads();

  const int wave = tid >> 6;
  const int lane = tid & 63;
  const int q = lane >> 4;     // quad
  const int c = lane & 15;     // column / m-row selector
  const int wgid = blockIdx.x * 8 + wave;
  char* hb = lds + LDS_HB + wave * 8192;

  // ---- per-lane persistent constants: biases (f32) + W1 B-fragments (bf16) ----
  float b1n[8], b2n[8], b3n[8];
  u32 w1a[8], w1b[8];
#pragma unroll
  for (int nt = 0; nt < 8; nt++) {
    int n = nt * 16 + c;
    b1n[nt] = B1g[n];
    b2n[nt] = B2g[n];
    b3n[nt] = B3g[n];
    // B-frag: lane(q,c) supplies B[k=8q+j][n=c]; only k<4 nonzero -> q==0 lanes, j<4
    u32 e01 = pk_bf16(W1g[n], W1g[128 + n]);
    u32 e23 = pk_bf16(W1g[256 + n], W1g[384 + n]);
    w1a[nt] = (q == 0) ? e01 : 0u;
    w1b[nt] = (q == 0) ? e23 : 0u;
  }
  const float b4v = B4g[c & 1];

  const int nbatch = npts >> 5;   // 32 points (2 tiles of 16) per wave-iteration
  for (int b = wgid; b < nbatch; b += nwaves_total) {
    const int pbase = b << 5;

    // ---- layer 1: A-frag directly from inputs (k = x,y,c1,c2, rest 0) ----
    u32 a0[2], a1[2];
#pragma unroll
    for (int t = 0; t < 2; t++) {
      int idx = pbase + t * 16 + c;
      a0[t] = pk_bf16(Xg[idx], Yg[idx]);     // j0,j1
      a1[t] = pk_bf16(C1g[idx], C2g[idx]);   // j2,j3
    }
#pragma unroll
    for (int nt = 0; nt < 8; nt++) {
      bf16x8 bw = mk_frag(w1a[nt], w1b[nt], 0u, 0u);
      f32x4 z = {0.f, 0.f, 0.f, 0.f};
      f32x4 acc0 = MFMA16(mk_frag(a0[0], a1[0], 0u, 0u), bw, z);
      f32x4 acc1 = MFMA16(mk_frag(a0[1], a1[1], 0u, 0u), bw, z);
#pragma unroll
      for (int r = 0; r < 4; r++) {
        float h0 = fast_tanh(acc0[r] + b1n[nt]);
        float h1 = fast_tanh(acc1[r] + b1n[nt]);
        int row = q * 4 + r;                       // C/D: row = quad*4 + reg
        int d = (nt * 16 + c) ^ (row << 2);        // col = lane&15 (+16*nt)
        *(u32*)(hb + row * 512 + d * 4) = pk_bf16(h0, h1);
      }
    }

    // ---- layers 2 and 3 (full 128x128 MFMA layers, in-place hbuf) ----
#pragma unroll
    for (int L = 0; L < 2; L++) {
      const char* wl = lds + (L ? LDS_W3 : LDS_W2);
      const float* bn = L ? b3n : b2n;
      u32 af0[4][4], af1[4][4];
#pragma unroll
      for (int ks = 0; ks < 4; ks++) {             // pre-read ALL A-frags before any write
        int d0 = ks * 32 + q * 8;
        u32x4 ra = *(const u32x4*)(hb + c * 512 + ((d0 ^ (c << 2)) << 2));
        u32x4 rb = *(const u32x4*)(hb + c * 512 + (((d0 + 4) ^ (c << 2)) << 2));
        af0[ks][0] = lo16(ra.x, ra.y); af1[ks][0] = hi16(ra.x, ra.y);
        af0[ks][1] = lo16(ra.z, ra.w); af1[ks][1] = hi16(ra.z, ra.w);
        af0[ks][2] = lo16(rb.x, rb.y); af1[ks][2] = hi16(rb.x, rb.y);
        af0[ks][3] = lo16(rb.z, rb.w); af1[ks][3] = hi16(rb.z, rb.w);
      }
#pragma unroll
      for (int nt = 0; nt < 8; nt++) {
        f32x4 acc0 = {0.f, 0.f, 0.f, 0.f}, acc1 = {0.f, 0.f, 0.f, 0.f};
#pragma unroll
        for (int ks = 0; ks < 4; ks++) {
          bf16x8 bw = *(const bf16x8*)(wl + (nt * 16 + c) * 256 + (((ks * 4 + q) ^ c) << 4));
          acc0 = MFMA16(mk_frag(af0[ks][0], af0[ks][1], af0[ks][2], af0[ks][3]), bw, acc0);
          acc1 = MFMA16(mk_frag(af1[ks][0], af1[ks][1], af1[ks][2], af1[ks][3]), bw, acc1);
        }
#pragma unroll
        for (int r = 0; r < 4; r++) {
          float h0 = fast_tanh(acc0[r] + bn[nt]);
          float h1 = fast_tanh(acc1[r] + bn[nt]);
          int row = q * 4 + r;
          int d = (nt * 16 + c) ^ (row << 2);
          *(u32*)(hb + row * 512 + d * 4) = pk_bf16(h0, h1);
        }
      }
    }

    // ---- layer 4 (N=2 in a padded N=16 tile) + f32 store ----
    {
      u32 af0[4][4], af1[4][4];
#pragma unroll
      for (int ks = 0; ks < 4; ks++) {
        int d0 = ks * 32 + q * 8;
        u32x4 ra = *(const u32x4*)(hb + c * 512 + ((d0 ^ (c << 2)) << 2));
        u32x4 rb = *(const u32x4*)(hb + c * 512 + (((d0 + 4) ^ (c << 2)) << 2));
        af0[ks][0] = lo16(ra.x, ra.y); af1[ks][0] = hi16(ra.x, ra.y);
        af0[ks][1] = lo16(ra.z, ra.w); af1[ks][1] = hi16(ra.z, ra.w);
        af0[ks][2] = lo16(rb.x, rb.y); af1[ks][2] = hi16(rb.x, rb.y);
        af0[ks][3] = lo16(rb.z, rb.w); af1[ks][3] = hi16(rb.z, rb.w);
      }
      f32x4 acc0 = {0.f, 0.f, 0.f, 0.f}, acc1 = {0.f, 0.f, 0.f, 0.f};
#pragma unroll
      for (int ks = 0; ks < 4; ks++) {
        // lanes c>=2 read row (c&1): duplicate logits land in unused output columns
        bf16x8 bw = *(const bf16x8*)(lds + LDS_W4 + (c & 1) * 256 + ((ks * 4 + q) << 4));
        acc0 = MFMA16(mk_frag(af0[ks][0], af0[ks][1], af0[ks][2], af0[ks][3]), bw, acc0);
        acc1 = MFMA16(mk_frag(af1[ks][0], af1[ks][1], af1[ks][2], af1[ks][3]), bw, acc1);
      }
      float o0[4], o1[4], pa[4], pb[4];
#pragma unroll
      for (int r = 0; r < 4; r++) {
        o0[r] = acc0[r] + b4v;
        o1[r] = acc1[r] + b4v;
        pa[r] = __shfl_xor(o0[r], 1);   // col-1 logit from lane c^1
        pb[r] = __shfl_xor(o1[r], 1);
      }
      if (c == 0) {
        // tile0: points pbase + q*4 + r, outputs (o0[r], pa[r]) as f32
        f32x4 s0a = {o0[0], pa[0], o0[1], pa[1]};
        f32x4 s0b = {o0[2], pa[2], o0[3], pa[3]};
        f32x4 s1a = {o1[0], pb[0], o1[1], pb[1]};
        f32x4 s1b = {o1[2], pb[2], o1[3], pb[3]};
        size_t base0 = (size_t)(pbase + q * 4) * 2;
        size_t base1 = (size_t)(pbase + 16 + q * 4) * 2;
        *(f32x4*)(Og + base0)     = s0a;
        *(f32x4*)(Og + base0 + 4) = s0b;
        *(f32x4*)(Og + base1)     = s1a;
        *(f32x4*)(Og + base1 + 4) = s1b;
      }
    }
  }
}

extern "C" void kernel_launch(void* const* d_in, const int* in_sizes, int n_in,
                              void* d_out, int out_size, void* d_ws, size_t ws_size,
                              hipStream_t stream)
{
  (void)n_in; (void)out_size; (void)d_ws; (void)ws_size;
  const float* X  = (const float*)d_in[0];
  const float* Y  = (const float*)d_in[1];
  const float* C1 = (const float*)d_in[2];
  const float* C2 = (const float*)d_in[3];
  const float* W1 = (const float*)d_in[4];
  const float* B1 = (const float*)d_in[5];
  const float* W2 = (const float*)d_in[6];
  const float* B2 = (const float*)d_in[7];
  const float* W3 = (const float*)d_in[8];
  const float* B3 = (const float*)d_in[9];
  const float* W4 = (const float*)d_in[10];
  const float* B4 = (const float*)d_in[11];
  int npts = in_sizes[0];
  const int nblk = 256;               // 1 WG/CU, 8 waves each
  const int nwaves = nblk * 8;
  hipLaunchKernelGGL(mlp_fused, dim3(nblk), dim3(512), LDS_TOTAL, stream,
                     X, Y, C1, C2, W1, B1, W2, B2, W3, B3, W4, B4,
                     (float*)d_out, npts, nwaves);
}